// Round 16
// baseline (229.711 us; speedup 1.0000x reference)
//
#include <hip/hip_runtime.h>
#include <hip/hip_bf16.h>
#include <cstdint>
#include <cstddef>

#define DIMD 1024
#define LSEQ 4096
#define BATCH 4
#define MTOT (BATCH*LSEQ)          // 16384
#define NCHUNK 64
#define CHUNKLEN 64
#define GATE_ELEMS ((size_t)MTOT*DIMD)
#define NTILE_K 32                 // 1024 / 32  (BK=32)

typedef __bf16 bf16x8 __attribute__((ext_vector_type(8)));
typedef float f32x16 __attribute__((ext_vector_type(16)));

__device__ __forceinline__ unsigned short f2bf(float f) {
    union { float f; uint32_t u; } v; v.f = f;
    uint32_t r = v.u + 0x7fffu + ((v.u >> 16) & 1u);   // RNE
    return (unsigned short)(r >> 16);
}
__device__ __forceinline__ float bits2f(unsigned short b) {
    union { uint32_t u; float f; } v; v.u = ((uint32_t)b) << 16; return v.f;
}
__device__ __forceinline__ float fsig(float x) {
    return __builtin_amdgcn_rcpf(1.f + __expf(-x));
}
__device__ __forceinline__ float ftanh(float x) {
    return 2.f * fsig(2.f * x) - 1.f;
}

// ---------------- fused cast fp32 -> bf16 (x + 4 weights, one launch) ----------------
__global__ void cast_all(const float* __restrict__ x,
                         const float* __restrict__ Wf, const float* __restrict__ Wi,
                         const float* __restrict__ Wig, const float* __restrict__ Wog,
                         unsigned short* __restrict__ Xb, unsigned short* __restrict__ Wcat) {
    int b = blockIdx.x;
    const float* src; unsigned short* dst; int lb;
    if (b < 8192) { src = x; dst = Xb; lb = b; }
    else {
        int w = (b - 8192) >> 9;             // 0..3 (512 blocks each)
        lb = (b - 8192) & 511;
        src = (w == 0) ? Wf : (w == 1) ? Wi : (w == 2) ? Wig : Wog;
        dst = Wcat + (size_t)w * DIMD * DIMD;
    }
    int i = (lb * 256 + threadIdx.x) * 8;
    float4 a = *(const float4*)(src + i);
    float4 c = *(const float4*)(src + i + 4);
    uint4 o;
    o.x = (uint32_t)f2bf(a.x) | ((uint32_t)f2bf(a.y) << 16);
    o.y = (uint32_t)f2bf(a.z) | ((uint32_t)f2bf(a.w) << 16);
    o.z = (uint32_t)f2bf(c.x) | ((uint32_t)f2bf(c.y) << 16);
    o.w = (uint32_t)f2bf(c.z) | ((uint32_t)f2bf(c.w) << 16);
    *(uint4*)(dst + i) = o;
}

// ---------------- gate-fused 128x(64e x 4 gates) GEMM + scan-phase1 fusion ----------------
// R16: MFMA shape 16x16x32 -> 32x32x16. Operand bytes & acc regs identical
// (2x2 f32x16 = 64), but MFMA pipe -17% (8x8.07 vs 16x4.85 cyc) and half the
// main-loop MFMA issue slots. C/D: row=(reg&3)+8*(reg>>2)+4*(lane>>5),
// col=lane&31 [m74/m101 HW-verified]; A/B: row=l&31, k=(l>>5)*8+j (duality as
// our verified 16x16 path). All LDS accesses re-derived 2-lanes/bank.
// Sync structure unchanged (vmcnt->barrier->sched_barrier; 3-buf depth-2).
__global__ __launch_bounds__(512, 4) void gemm_gates_f(
    const unsigned short* __restrict__ Xb,    // [16384][1024] bf16 bits
    const unsigned short* __restrict__ Wcat,  // [4][1024][1024] bf16 bits
    const float* __restrict__ bf_, const float* __restrict__ bi_,
    const float* __restrict__ big_, const float* __restrict__ bog_,
    unsigned short* __restrict__ F, unsigned short* __restrict__ I,
    unsigned short* __restrict__ OG,
    float* __restrict__ Aagg, float* __restrict__ Bagg)
{
    __shared__ __align__(16) char lds[73728];   // A: 3x8KB @0 ; B: 3x16KB @24576
    char* ldsA = lds;
    char* ldsB = lds + 24576;

    const int tid = threadIdx.x;
    const int wave = tid >> 6, lane = tid & 63;
    const int wm = wave >> 2, wn = wave & 3;       // wm: row half, wn: GATE
    const int l31 = lane & 31, lh = lane >> 5;     // frag row, k-half

    // T1: XCD-rectangle swizzle (2048 blocks, bijective)
    const int wg = blockIdx.x;
    const int xcd = wg & 7, rr = wg >> 3;
    const int mt = xcd * 16 + (rr & 15);           // 0..127
    const int et = rr >> 4;                        // 0..15
    const int m0 = mt * 128, e0 = et * 64;

    // ---- swizzled LDS read bases (row=64B, 4 slots, XOR (row>>1)&3) ----
    const int swzr = (l31 >> 1) & 3;
    const char* ArdK0 = ldsA + (wm * 64 + l31) * 64 + ((lh ^ swzr) << 4);
    const char* ArdK1 = ldsA + (wm * 64 + l31) * 64 + (((2 + lh) ^ swzr) << 4);
    const char* BrdK0 = ldsB + (wn * 64 + l31) * 64 + ((lh ^ swzr) << 4);
    const char* BrdK1 = ldsB + (wn * 64 + l31) * 64 + (((2 + lh) ^ swzr) << 4);

    // ---- per-thread stage source bases (inverse swizzle on global col) ----
    const int srow = tid >> 2;                             // 0..127
    const int scg  = ((tid & 3) ^ ((srow >> 1) & 3)) * 8;
    const unsigned short* pAsrc = Xb + (size_t)(m0 + srow) * DIMD + scg;
    // B LDS rows 0..127 = gates 0,1 ; 128..255 = gates 2,3 (64 e-cols each)
    const unsigned short* pBsrc0 = Wcat + (size_t)((srow >> 6) * 1024 + e0 + (srow & 63)) * DIMD + scg;
    const unsigned short* pBsrc1 = Wcat + (size_t)((2 + (srow >> 6)) * 1024 + e0 + (srow & 63)) * DIMD + scg;

    auto stage3 = [&](int k0, int offA, int offB) {
        __builtin_amdgcn_global_load_lds(
            (const __attribute__((address_space(1))) uint32_t*)(pAsrc + k0),
            (__attribute__((address_space(3))) uint32_t*)(ldsA + offA + (wave << 10)), 16, 0, 0);
        __builtin_amdgcn_global_load_lds(
            (const __attribute__((address_space(1))) uint32_t*)(pBsrc0 + k0),
            (__attribute__((address_space(3))) uint32_t*)(ldsB + offB + (wave << 10)), 16, 0, 0);
        __builtin_amdgcn_global_load_lds(
            (const __attribute__((address_space(1))) uint32_t*)(pBsrc1 + k0),
            (__attribute__((address_space(3))) uint32_t*)(ldsB + offB + 8192 + (wave << 10)), 16, 0, 0);
    };

    f32x16 acc[2][2];
#pragma unroll
    for (int mi = 0; mi < 2; ++mi)
#pragma unroll
        for (int ni = 0; ni < 2; ++ni) acc[mi][ni] = (f32x16)0.f;

    // prologue: stage tiles 0 and 1
    stage3(0, 0, 0);
    stage3(32, 8192, 16384);

    int offA0 = 0, offA1 = 8192, offA2 = 16384;
    int offB0 = 0, offB1 = 16384, offB2 = 32768;
#pragma unroll 1
    for (int t = 0; t < NTILE_K; ++t) {
        if (t <= NTILE_K - 2) asm volatile("s_waitcnt vmcnt(3)" ::: "memory");
        else                  asm volatile("s_waitcnt vmcnt(0)" ::: "memory");
        __builtin_amdgcn_s_barrier();          // all waves' tile-t loads landed
        __builtin_amdgcn_sched_barrier(0);

        if (t + 2 < NTILE_K) stage3((t + 2) * 32, offA2, offB2);

        bf16x8 av[2][2], bv[2][2];
#pragma unroll
        for (int mi = 0; mi < 2; ++mi) {
            av[mi][0] = *(const bf16x8*)(ArdK0 + offA0 + mi * 2048);
            av[mi][1] = *(const bf16x8*)(ArdK1 + offA0 + mi * 2048);
        }
#pragma unroll
        for (int ni = 0; ni < 2; ++ni) {
            bv[ni][0] = *(const bf16x8*)(BrdK0 + offB0 + ni * 2048);
            bv[ni][1] = *(const bf16x8*)(BrdK1 + offB0 + ni * 2048);
        }

        __builtin_amdgcn_s_setprio(1);
#pragma unroll
        for (int kk = 0; kk < 2; ++kk)
#pragma unroll
            for (int mi = 0; mi < 2; ++mi)
#pragma unroll
                for (int ni = 0; ni < 2; ++ni)
                    acc[mi][ni] = __builtin_amdgcn_mfma_f32_32x32x16_bf16(
                        av[mi][kk], bv[ni][kk], acc[mi][ni], 0, 0, 0);
        __builtin_amdgcn_s_setprio(0);

        int ta = offA0; offA0 = offA1; offA1 = offA2; offA2 = ta;
        int tb = offB0; offB0 = offB1; offB1 = offB2; offB2 = tb;
    }

    // ================= epilogue =================
    // C/D frag: within-wave row = mi*32 + q*8 + lh*4 + rq  (reg r = q*4+rq),
    //           col = ni*32 + l31
    const float* biasg = (wn == 0) ? bf_ : (wn == 1) ? bi_ : (wn == 2) ? big_ : bog_;
    float bvv[2];
#pragma unroll
    for (int ni = 0; ni < 2; ++ni) bvv[ni] = biasg[e0 + ni * 32 + l31];

    // activation in place (wn==1 -> tanh, else sigmoid)
#pragma unroll
    for (int mi = 0; mi < 2; ++mi)
#pragma unroll
        for (int ni = 0; ni < 2; ++ni)
#pragma unroll
            for (int r = 0; r < 16; ++r) {
                float pre = acc[mi][ni][r] + bvv[ni];
                acc[mi][ni][r] = (wn == 1) ? ftanh(pre) : fsig(pre);
            }

    // cross-wave handoff: f (wn0, f32) sg (wn2, f32) ti-upper-half (wn1, bf16)
    float* ldsF  = (float*)lds;                               // [2][64][64] f32 = 32 KB
    float* ldsSG = (float*)(lds + 32768);                     // [2][64][64] f32 = 32 KB
    unsigned short* ldsTIh = (unsigned short*)(lds + 65536);  // [2][64][32] u16 =  8 KB
    __builtin_amdgcn_s_barrier();            // barrier1: main-loop LDS fully consumed
    if (wn == 0 || wn == 2) {
        float* dstL = (wn == 0 ? ldsF : ldsSG) + wm * 4096;
#pragma unroll
        for (int mi = 0; mi < 2; ++mi)
#pragma unroll
            for (int q = 0; q < 4; ++q)
#pragma unroll
                for (int rq = 0; rq < 4; ++rq) {
                    int row = mi * 32 + q * 8 + lh * 4 + rq;
#pragma unroll
                    for (int ni = 0; ni < 2; ++ni)
                        dstL[row * 64 + ni * 32 + l31] = acc[mi][ni][q * 4 + rq];
                }
    } else if (wn == 1) {
        unsigned short* tD = ldsTIh + wm * 2048;
#pragma unroll
        for (int mi = 0; mi < 2; ++mi)
#pragma unroll
            for (int q = 0; q < 4; ++q)
#pragma unroll
                for (int rq = 0; rq < 4; ++rq) {
                    int row = mi * 32 + q * 8 + lh * 4 + rq;
                    tD[row * 32 + l31] = f2bf(acc[mi][1][q * 4 + rq]);
                }
    }
    asm volatile("s_waitcnt lgkmcnt(0)" ::: "memory");
    __builtin_amdgcn_s_barrier();            // barrier2: handoff visible

    const size_t rowbase = (size_t)(m0 + wm * 64) * DIMD + e0;
    const int gc = (m0 >> 6) + wm;           // global chunk id (b*64+c)
    if (wn == 0 || wn == 3) {
        unsigned short* dstG = (wn == 0) ? F : OG;
#pragma unroll
        for (int mi = 0; mi < 2; ++mi)
#pragma unroll
            for (int q = 0; q < 4; ++q)
#pragma unroll
                for (int rq = 0; rq < 4; ++rq) {
                    int row = mi * 32 + q * 8 + lh * 4 + rq;
                    size_t ro = rowbase + (size_t)row * DIMD;
#pragma unroll
                    for (int ni = 0; ni < 2; ++ni)
                        dstG[ro + ni * 32 + l31] = f2bf(acc[mi][ni][q * 4 + rq]);
                }
    } else if (wn == 1) {
        // lower e-half (cols l31): i = ti(reg) * sg(LDS); I-store; aggregates
        const float* fL  = ldsF  + wm * 4096;
        const float* sgL = ldsSG + wm * 4096;
        float A = 1.f, Bv = 0.f;
#pragma unroll
        for (int mi = 0; mi < 2; ++mi)
#pragma unroll
            for (int q = 0; q < 4; ++q) {
                float sA = 1.f, sB = 0.f;
#pragma unroll
                for (int rq = 0; rq < 4; ++rq) {
                    int row = mi * 32 + q * 8 + lh * 4 + rq;
                    float fv = fL[row * 64 + l31];
                    float iv = acc[mi][0][q * 4 + rq] * sgL[row * 64 + l31];
                    I[rowbase + (size_t)row * DIMD + l31] = f2bf(iv);
                    sA = fv * sA;
                    sB = __builtin_fmaf(fv, sB, iv);
                }
                // 1-bit butterfly across lh (rows +4)
                {
                    float Ap = __shfl_xor(sA, 32, 64);
                    float Bp = __shfl_xor(sB, 32, 64);
                    bool later = lh != 0;
                    float aE = later ? Ap : sA, bE = later ? Bp : sB;
                    float aL = later ? sA : Ap, bL = later ? sB : Bp;
                    sA = aE * aL;
                    sB = __builtin_fmaf(aL, bE, bL);
                }
                Bv = __builtin_fmaf(sA, Bv, sB);
                A  = A * sA;
            }
        if (lh == 0) {
            int e = e0 + l31;
            Aagg[(size_t)gc * DIMD + e] = A;
            Bagg[(size_t)gc * DIMD + e] = Bv;
        }
    } else {
        // wn==2: upper e-half (cols 32+l31): i = ti(LDS bf16) * sg(own regs)
        const float* fL  = ldsF + wm * 4096;
        const unsigned short* tiL = ldsTIh + wm * 2048;
        float A = 1.f, Bv = 0.f;
#pragma unroll
        for (int mi = 0; mi < 2; ++mi)
#pragma unroll
            for (int q = 0; q < 4; ++q) {
                float sA = 1.f, sB = 0.f;
#pragma unroll
                for (int rq = 0; rq < 4; ++rq) {
                    int row = mi * 32 + q * 8 + lh * 4 + rq;
                    float fv = fL[row * 64 + 32 + l31];
                    float iv = bits2f(tiL[row * 32 + l31]) * acc[mi][1][q * 4 + rq];
                    I[rowbase + (size_t)row * DIMD + 32 + l31] = f2bf(iv);
                    sA = fv * sA;
                    sB = __builtin_fmaf(fv, sB, iv);
                }
                {
                    float Ap = __shfl_xor(sA, 32, 64);
                    float Bp = __shfl_xor(sB, 32, 64);
                    bool later = lh != 0;
                    float aE = later ? Ap : sA, bE = later ? Bp : sB;
                    float aL = later ? sA : Ap, bL = later ? sB : Bp;
                    sA = aE * aL;
                    sB = __builtin_fmaf(aL, bE, bL);
                }
                Bv = __builtin_fmaf(sA, Bv, sB);
                A  = A * sA;
            }
        if (lh == 0) {
            int e = e0 + 32 + l31;
            Aagg[(size_t)gc * DIMD + e] = A;
            Bagg[(size_t)gc * DIMD + e] = Bv;
        }
    }
}

// ---------------- scan phase 2: batched chunk-aggregate scan ----------------
__global__ void scan_phase2(const float* __restrict__ Aagg, const float* __restrict__ Bagg,
                            const float* __restrict__ hidden,
                            float* __restrict__ Hstart, float* __restrict__ out_h) {
    int idx = blockIdx.x * blockDim.x + threadIdx.x;  // 0..4095
    int b = idx >> 10, d = idx & 1023;
    float h = hidden[b * 1024 + d];
    size_t base = (size_t)b * NCHUNK * DIMD + d;
    float Av[NCHUNK], Bv[NCHUNK];
#pragma unroll
    for (int c = 0; c < NCHUNK; ++c) {
        Av[c] = Aagg[base + (size_t)c * DIMD];
        Bv[c] = Bagg[base + (size_t)c * DIMD];
    }
#pragma unroll
    for (int c = 0; c < NCHUNK; ++c) {
        Hstart[base + (size_t)c * DIMD] = h;
        h = __builtin_fmaf(Av[c], h, Bv[c]);
    }
    out_h[b * 1024 + d] = h;
}

// ---------------- scan phase 3: replay chunk with prefix, write y (vectorized x4) ----------------
__global__ void scan_phase3(const unsigned short* __restrict__ F,
                            const unsigned short* __restrict__ I,
                            const unsigned short* __restrict__ OG,
                            const float* __restrict__ Hstart, float* __restrict__ y) {
    const int d0 = threadIdx.x * 4;
    const int c = blockIdx.x, b = blockIdx.y;
    size_t ho = ((size_t)b * NCHUNK + c) * DIMD + d0;
    float4 h4 = *(const float4*)(Hstart + ho);
    float h0 = h4.x, h1 = h4.y, h2 = h4.z, h3 = h4.w;
    size_t base = ((size_t)b * LSEQ + (size_t)c * CHUNKLEN) * DIMD + d0;
#pragma unroll 4
    for (int t = 0; t < CHUNKLEN; ++t) {
        size_t off = base + (size_t)t * DIMD;
        ushort4 fv = *(const ushort4*)(F + off);
        ushort4 iv = *(const ushort4*)(I + off);
        ushort4 gv = *(const ushort4*)(OG + off);
        float4 o;
        h0 = __builtin_fmaf(bits2f(fv.x), h0, bits2f(iv.x)); o.x = ftanh(h0) * bits2f(gv.x);
        h1 = __builtin_fmaf(bits2f(fv.y), h1, bits2f(iv.y)); o.y = ftanh(h1) * bits2f(gv.y);
        h2 = __builtin_fmaf(bits2f(fv.z), h2, bits2f(iv.z)); o.z = ftanh(h2) * bits2f(gv.z);
        h3 = __builtin_fmaf(bits2f(fv.w), h3, bits2f(iv.w)); o.w = ftanh(h3) * bits2f(gv.w);
        *(float4*)(y + off) = o;
    }
}

// ---------------- launch ----------------
extern "C" void kernel_launch(void* const* d_in, const int* in_sizes, int n_in,
                              void* d_out, int out_size, void* d_ws, size_t ws_size,
                              hipStream_t stream) {
    const float* x      = (const float*)d_in[0];
    const float* hidden = (const float*)d_in[1];
    const float* Wf  = (const float*)d_in[2];
    const float* bf_ = (const float*)d_in[3];
    const float* Wi  = (const float*)d_in[4];
    const float* bi_ = (const float*)d_in[5];
    const float* Wig = (const float*)d_in[6];
    const float* big_= (const float*)d_in[7];
    const float* Wog = (const float*)d_in[8];
    const float* bog_= (const float*)d_in[9];

    char* ws = (char*)d_ws;
    unsigned short* Xb   = (unsigned short*)(ws);             // 33,554,432 B
    unsigned short* Wcat = (unsigned short*)(ws + 33554432);  //  8,388,608 B
    unsigned short* F    = (unsigned short*)(ws + 41943040);  // 33,554,432 B
    unsigned short* I    = (unsigned short*)(ws + 75497472);  // 33,554,432 B
    unsigned short* OG   = (unsigned short*)(ws + 109051904); // 33,554,432 B
    float* Aagg   = (float*)(ws + 142606336);                 //  1,048,576 B
    float* Bagg   = (float*)(ws + 143654912);                 //  1,048,576 B
    float* Hstart = (float*)(ws + 144703488);                 //  1,048,576 B
    // total ws need: 145,752,064 B

    float* y     = (float*)d_out;                 // [4][4096][1024]
    float* out_h = y + GATE_ELEMS;                // [4][1024]

    // fused casts (x: 8192 blocks, weights: 4 x 512 blocks)
    cast_all<<<10240, 256, 0, stream>>>(x, Wf, Wi, Wig, Wog, Xb, Wcat);

    // gate-fused GEMM + activations + i-product + scan-phase1 aggregates
    gemm_gates_f<<<2048, 512, 0, stream>>>(Xb, Wcat, bf_, bi_, big_, bog_,
                                           F, I, OG, Aagg, Bagg);

    // chunk-prefix scan + replay
    scan_phase2<<<BATCH * DIMD / 256, 256, 0, stream>>>(Aagg, Bagg, hidden, Hstart, out_h);
    scan_phase3<<<dim3(NCHUNK, BATCH), 256, 0, stream>>>(F, I, OG, Hstart, y);
}

// Round 17
// 212.515 us; speedup vs baseline: 1.0809x; 1.0809x over previous
//
#include <hip/hip_runtime.h>
#include <hip/hip_bf16.h>
#include <cstdint>
#include <cstddef>

#define DIMD 1024
#define LSEQ 4096
#define BATCH 4
#define MTOT (BATCH*LSEQ)          // 16384
#define NCHUNK 64
#define CHUNKLEN 64
#define GATE_ELEMS ((size_t)MTOT*DIMD)
#define NTILE_K 32                 // 1024 / 32  (BK=32)

typedef __bf16 bf16x8 __attribute__((ext_vector_type(8)));
typedef float f32x4 __attribute__((ext_vector_type(4)));

__device__ __forceinline__ unsigned short f2bf(float f) {
    union { float f; uint32_t u; } v; v.f = f;
    uint32_t r = v.u + 0x7fffu + ((v.u >> 16) & 1u);   // RNE
    return (unsigned short)(r >> 16);
}
__device__ __forceinline__ float bits2f(unsigned short b) {
    union { uint32_t u; float f; } v; v.u = ((uint32_t)b) << 16; return v.f;
}
__device__ __forceinline__ float fsig(float x) {
    return __builtin_amdgcn_rcpf(1.f + __expf(-x));
}
__device__ __forceinline__ float ftanh(float x) {
    return 2.f * fsig(2.f * x) - 1.f;
}

// ---------------- fused cast fp32 -> bf16 (x + 4 weights, one launch) ----------------
__global__ void cast_all(const float* __restrict__ x,
                         const float* __restrict__ Wf, const float* __restrict__ Wi,
                         const float* __restrict__ Wig, const float* __restrict__ Wog,
                         unsigned short* __restrict__ Xb, unsigned short* __restrict__ Wcat) {
    int b = blockIdx.x;
    const float* src; unsigned short* dst; int lb;
    if (b < 8192) { src = x; dst = Xb; lb = b; }
    else {
        int w = (b - 8192) >> 9;             // 0..3 (512 blocks each)
        lb = (b - 8192) & 511;
        src = (w == 0) ? Wf : (w == 1) ? Wi : (w == 2) ? Wig : Wog;
        dst = Wcat + (size_t)w * DIMD * DIMD;
    }
    int i = (lb * 256 + threadIdx.x) * 8;
    float4 a = *(const float4*)(src + i);
    float4 c = *(const float4*)(src + i + 4);
    uint4 o;
    o.x = (uint32_t)f2bf(a.x) | ((uint32_t)f2bf(a.y) << 16);
    o.y = (uint32_t)f2bf(a.z) | ((uint32_t)f2bf(a.w) << 16);
    o.z = (uint32_t)f2bf(c.x) | ((uint32_t)f2bf(c.y) << 16);
    o.w = (uint32_t)f2bf(c.z) | ((uint32_t)f2bf(c.w) << 16);
    *(uint4*)(dst + i) = o;
}

// ---------------- gate-fused 128x(64e x 4 gates) GEMM + scan-phase1 fusion ----------------
// R17 = byte-level revert to R15 (best measured: gemm 162.5us, 0-conflict main
// loop with the 16-row x 4-slot XOR swizzle that MEASURED zero; R16's 32x32
// 2-slot variant re-introduced 4-way conflicts). XCD-rectangle swizzle kept.
__global__ __launch_bounds__(512, 4) void gemm_gates_f(
    const unsigned short* __restrict__ Xb,    // [16384][1024] bf16 bits
    const unsigned short* __restrict__ Wcat,  // [4][1024][1024] bf16 bits
    const float* __restrict__ bf_, const float* __restrict__ bi_,
    const float* __restrict__ big_, const float* __restrict__ bog_,
    unsigned short* __restrict__ F, unsigned short* __restrict__ I,
    unsigned short* __restrict__ OG,
    float* __restrict__ Aagg, float* __restrict__ Bagg)
{
    __shared__ __align__(16) char lds[73728];   // A: 3x8KB @0 ; B: 3x16KB @24576
    char* ldsA = lds;
    char* ldsB = lds + 24576;

    const int tid = threadIdx.x;
    const int wave = tid >> 6, lane = tid & 63;
    const int wm = wave >> 2, wn = wave & 3;       // wm: row half, wn: GATE
    const int l15 = lane & 15, l4 = lane >> 4;

    // T1: XCD-rectangle swizzle (2048 blocks, bijective)
    const int wg = blockIdx.x;
    const int xcd = wg & 7, rr = wg >> 3;
    const int mt = xcd * 16 + (rr & 15);           // 0..127
    const int et = rr >> 4;                        // 0..15
    const int m0 = mt * 128, e0 = et * 64;

    // ---- swizzled LDS read bases ----
    const int rsw = (l4 ^ ((l15 >> 1) & 3)) << 4;
    const char* ArdBase = ldsA + (wm * 64 + l15) * 64 + rsw;
    const char* BrdBase = ldsB + (wn * 64 + l15) * 64 + rsw;

    // ---- per-thread stage source bases (inverse swizzle on global col) ----
    const int srow = tid >> 2;                             // 0..127
    const int scg  = ((tid & 3) ^ ((srow >> 1) & 3)) * 8;
    const unsigned short* pAsrc = Xb + (size_t)(m0 + srow) * DIMD + scg;
    // B LDS rows 0..127 = gates 0,1 ; 128..255 = gates 2,3 (64 e-cols each)
    const unsigned short* pBsrc0 = Wcat + (size_t)((srow >> 6) * 1024 + e0 + (srow & 63)) * DIMD + scg;
    const unsigned short* pBsrc1 = Wcat + (size_t)((2 + (srow >> 6)) * 1024 + e0 + (srow & 63)) * DIMD + scg;

    auto stage3 = [&](int k0, int offA, int offB) {
        __builtin_amdgcn_global_load_lds(
            (const __attribute__((address_space(1))) uint32_t*)(pAsrc + k0),
            (__attribute__((address_space(3))) uint32_t*)(ldsA + offA + (wave << 10)), 16, 0, 0);
        __builtin_amdgcn_global_load_lds(
            (const __attribute__((address_space(1))) uint32_t*)(pBsrc0 + k0),
            (__attribute__((address_space(3))) uint32_t*)(ldsB + offB + (wave << 10)), 16, 0, 0);
        __builtin_amdgcn_global_load_lds(
            (const __attribute__((address_space(1))) uint32_t*)(pBsrc1 + k0),
            (__attribute__((address_space(3))) uint32_t*)(ldsB + offB + 8192 + (wave << 10)), 16, 0, 0);
    };

    f32x4 acc[4][4];
#pragma unroll
    for (int m = 0; m < 4; ++m)
#pragma unroll
        for (int n = 0; n < 4; ++n) acc[m][n] = (f32x4)0.f;

    // prologue: stage tiles 0 and 1
    stage3(0, 0, 0);
    stage3(32, 8192, 16384);

    int offA0 = 0, offA1 = 8192, offA2 = 16384;
    int offB0 = 0, offB1 = 16384, offB2 = 32768;
#pragma unroll 1
    for (int t = 0; t < NTILE_K; ++t) {
        if (t <= NTILE_K - 2) asm volatile("s_waitcnt vmcnt(3)" ::: "memory");
        else                  asm volatile("s_waitcnt vmcnt(0)" ::: "memory");
        __builtin_amdgcn_s_barrier();          // all waves' tile-t loads landed
        __builtin_amdgcn_sched_barrier(0);

        if (t + 2 < NTILE_K) stage3((t + 2) * 32, offA2, offB2);

        bf16x8 bv[4], avl[2], avh[2];
#pragma unroll
        for (int n = 0; n < 4; ++n)
            bv[n] = *(const bf16x8*)(BrdBase + offB0 + n * 1024);
        avl[0] = *(const bf16x8*)(ArdBase + offA0);
        avl[1] = *(const bf16x8*)(ArdBase + offA0 + 1024);

        __builtin_amdgcn_s_setprio(1);
#pragma unroll
        for (int m = 0; m < 2; ++m)
#pragma unroll
            for (int n = 0; n < 4; ++n)
                acc[m][n] = __builtin_amdgcn_mfma_f32_16x16x32_bf16(avl[m], bv[n], acc[m][n], 0, 0, 0);
        __builtin_amdgcn_s_setprio(0);

        avh[0] = *(const bf16x8*)(ArdBase + offA0 + 2048);
        avh[1] = *(const bf16x8*)(ArdBase + offA0 + 3072);

        __builtin_amdgcn_s_setprio(1);
#pragma unroll
        for (int m = 0; m < 2; ++m)
#pragma unroll
            for (int n = 0; n < 4; ++n)
                acc[2 + m][n] = __builtin_amdgcn_mfma_f32_16x16x32_bf16(avh[m], bv[n], acc[2 + m][n], 0, 0, 0);
        __builtin_amdgcn_s_setprio(0);

        int ta = offA0; offA0 = offA1; offA1 = offA2; offA2 = ta;
        int tb = offB0; offB0 = offB1; offB1 = offB2; offB2 = tb;
    }

    // ================= epilogue =================
    const float* biasg = (wn == 0) ? bf_ : (wn == 1) ? bi_ : (wn == 2) ? big_ : bog_;
    float bvv[4];
#pragma unroll
    for (int nf = 0; nf < 4; ++nf) bvv[nf] = biasg[e0 + nf * 16 + l15];

    // activation in place (wn==1 -> tanh, else sigmoid)
#pragma unroll
    for (int mf = 0; mf < 4; ++mf)
#pragma unroll
        for (int nf = 0; nf < 4; ++nf)
#pragma unroll
            for (int r = 0; r < 4; ++r) {
                float pre = acc[mf][nf][r] + bvv[nf];
                acc[mf][nf][r] = (wn == 1) ? ftanh(pre) : fsig(pre);
            }

    // cross-wave handoff: f (wn0, f32) sg (wn2, f32) ti-upper-half (wn1, bf16)
    float* ldsF  = (float*)lds;                               // [2][64][64] f32 = 32 KB
    float* ldsSG = (float*)(lds + 32768);                     // [2][64][64] f32 = 32 KB
    unsigned short* ldsTIh = (unsigned short*)(lds + 65536);  // [2][64][32] u16 =  8 KB
    __builtin_amdgcn_s_barrier();            // barrier1: main-loop LDS fully consumed
    if (wn == 0 || wn == 2) {
        float* dstL = (wn == 0 ? ldsF : ldsSG) + wm * 4096;
#pragma unroll
        for (int mf = 0; mf < 4; ++mf)
#pragma unroll
            for (int nf = 0; nf < 4; ++nf)
#pragma unroll
                for (int r = 0; r < 4; ++r)
                    dstL[(mf * 16 + l4 * 4 + r) * 64 + nf * 16 + l15] = acc[mf][nf][r];
    } else if (wn == 1) {
        unsigned short* tD = ldsTIh + wm * 2048;
#pragma unroll
        for (int mf = 0; mf < 4; ++mf)
#pragma unroll
            for (int nfi = 0; nfi < 2; ++nfi)
#pragma unroll
                for (int r = 0; r < 4; ++r)
                    tD[(mf * 16 + l4 * 4 + r) * 32 + nfi * 16 + l15] = f2bf(acc[mf][2 + nfi][r]);
    }
    asm volatile("s_waitcnt lgkmcnt(0)" ::: "memory");
    __builtin_amdgcn_s_barrier();            // barrier2: handoff visible

    const size_t rowbase = (size_t)(m0 + wm * 64) * DIMD + e0;
    const int gc = (m0 >> 6) + wm;           // global chunk id (b*64+c)
    if (wn == 0) {
        // store F
#pragma unroll
        for (int mf = 0; mf < 4; ++mf)
#pragma unroll
            for (int r = 0; r < 4; ++r) {
                size_t ro = rowbase + (size_t)(mf * 16 + l4 * 4 + r) * DIMD;
#pragma unroll
                for (int nf = 0; nf < 4; ++nf)
                    F[ro + nf * 16 + l15] = f2bf(acc[mf][nf][r]);
            }
    } else if (wn == 3) {
        // store OG
#pragma unroll
        for (int mf = 0; mf < 4; ++mf)
#pragma unroll
            for (int r = 0; r < 4; ++r) {
                size_t ro = rowbase + (size_t)(mf * 16 + l4 * 4 + r) * DIMD;
#pragma unroll
                for (int nf = 0; nf < 4; ++nf)
                    OG[ro + nf * 16 + l15] = f2bf(acc[mf][nf][r]);
            }
    } else if (wn == 1) {
        // lower nf half: i = ti(reg) * sg(LDS); I-store; aggregates
        const float* fL  = ldsF  + wm * 4096;
        const float* sgL = ldsSG + wm * 4096;
#pragma unroll
        for (int nf = 0; nf < 2; ++nf) {
            float A = 1.f, Bv = 0.f;
#pragma unroll
            for (int mf = 0; mf < 4; ++mf) {
                float sA = 1.f, sB = 0.f;
#pragma unroll
                for (int r = 0; r < 4; ++r) {
                    int row = mf * 16 + l4 * 4 + r;
                    int ecl = nf * 16 + l15;
                    float fv = fL[row * 64 + ecl];
                    float iv = acc[mf][nf][r] * sgL[row * 64 + ecl];
                    I[rowbase + (size_t)row * DIMD + ecl] = f2bf(iv);
                    sA = fv * sA;
                    sB = __builtin_fmaf(fv, sB, iv);
                }
#pragma unroll
                for (int s = 16; s <= 32; s <<= 1) {
                    float Ap = __shfl_xor(sA, s, 64);
                    float Bp = __shfl_xor(sB, s, 64);
                    bool later = (lane & s) != 0;
                    float aE = later ? Ap : sA, bE = later ? Bp : sB;
                    float aL = later ? sA : Ap, bL = later ? sB : Bp;
                    sA = aE * aL;
                    sB = __builtin_fmaf(aL, bE, bL);
                }
                Bv = __builtin_fmaf(sA, Bv, sB);
                A  = A * sA;
            }
            if (l4 == 0) {
                int e = e0 + nf * 16 + l15;
                Aagg[(size_t)gc * DIMD + e] = A;
                Bagg[(size_t)gc * DIMD + e] = Bv;
            }
        }
    } else {
        // wn==2: upper nf half: i = ti(LDS bf16) * sg(own regs); I-store; aggregates
        const float* fL  = ldsF + wm * 4096;
        const unsigned short* tiL = ldsTIh + wm * 2048;
#pragma unroll
        for (int nfi = 0; nfi < 2; ++nfi) {
            const int nf = 2 + nfi;
            float A = 1.f, Bv = 0.f;
#pragma unroll
            for (int mf = 0; mf < 4; ++mf) {
                float sA = 1.f, sB = 0.f;
#pragma unroll
                for (int r = 0; r < 4; ++r) {
                    int row = mf * 16 + l4 * 4 + r;
                    int ecl = nf * 16 + l15;
                    float fv = fL[row * 64 + ecl];
                    float iv = bits2f(tiL[row * 32 + nfi * 16 + l15]) * acc[mf][nf][r];
                    I[rowbase + (size_t)row * DIMD + ecl] = f2bf(iv);
                    sA = fv * sA;
                    sB = __builtin_fmaf(fv, sB, iv);
                }
#pragma unroll
                for (int s = 16; s <= 32; s <<= 1) {
                    float Ap = __shfl_xor(sA, s, 64);
                    float Bp = __shfl_xor(sB, s, 64);
                    bool later = (lane & s) != 0;
                    float aE = later ? Ap : sA, bE = later ? Bp : sB;
                    float aL = later ? sA : Ap, bL = later ? sB : Bp;
                    sA = aE * aL;
                    sB = __builtin_fmaf(aL, bE, bL);
                }
                Bv = __builtin_fmaf(sA, Bv, sB);
                A  = A * sA;
            }
            if (l4 == 0) {
                int e = e0 + nf * 16 + l15;
                Aagg[(size_t)gc * DIMD + e] = A;
                Bagg[(size_t)gc * DIMD + e] = Bv;
            }
        }
    }
}

// ---------------- scan phase 2: batched chunk-aggregate scan ----------------
__global__ void scan_phase2(const float* __restrict__ Aagg, const float* __restrict__ Bagg,
                            const float* __restrict__ hidden,
                            float* __restrict__ Hstart, float* __restrict__ out_h) {
    int idx = blockIdx.x * blockDim.x + threadIdx.x;  // 0..4095
    int b = idx >> 10, d = idx & 1023;
    float h = hidden[b * 1024 + d];
    size_t base = (size_t)b * NCHUNK * DIMD + d;
    float Av[NCHUNK], Bv[NCHUNK];
#pragma unroll
    for (int c = 0; c < NCHUNK; ++c) {
        Av[c] = Aagg[base + (size_t)c * DIMD];
        Bv[c] = Bagg[base + (size_t)c * DIMD];
    }
#pragma unroll
    for (int c = 0; c < NCHUNK; ++c) {
        Hstart[base + (size_t)c * DIMD] = h;
        h = __builtin_fmaf(Av[c], h, Bv[c]);
    }
    out_h[b * 1024 + d] = h;
}

// ---------------- scan phase 3: replay chunk with prefix, write y (vectorized x4) ----------------
__global__ void scan_phase3(const unsigned short* __restrict__ F,
                            const unsigned short* __restrict__ I,
                            const unsigned short* __restrict__ OG,
                            const float* __restrict__ Hstart, float* __restrict__ y) {
    const int d0 = threadIdx.x * 4;
    const int c = blockIdx.x, b = blockIdx.y;
    size_t ho = ((size_t)b * NCHUNK + c) * DIMD + d0;
    float4 h4 = *(const float4*)(Hstart + ho);
    float h0 = h4.x, h1 = h4.y, h2 = h4.z, h3 = h4.w;
    size_t base = ((size_t)b * LSEQ + (size_t)c * CHUNKLEN) * DIMD + d0;
#pragma unroll 4
    for (int t = 0; t < CHUNKLEN; ++t) {
        size_t off = base + (size_t)t * DIMD;
        ushort4 fv = *(const ushort4*)(F + off);
        ushort4 iv = *(const ushort4*)(I + off);
        ushort4 gv = *(const ushort4*)(OG + off);
        float4 o;
        h0 = __builtin_fmaf(bits2f(fv.x), h0, bits2f(iv.x)); o.x = ftanh(h0) * bits2f(gv.x);
        h1 = __builtin_fmaf(bits2f(fv.y), h1, bits2f(iv.y)); o.y = ftanh(h1) * bits2f(gv.y);
        h2 = __builtin_fmaf(bits2f(fv.z), h2, bits2f(iv.z)); o.z = ftanh(h2) * bits2f(gv.z);
        h3 = __builtin_fmaf(bits2f(fv.w), h3, bits2f(iv.w)); o.w = ftanh(h3) * bits2f(gv.w);
        *(float4*)(y + off) = o;
    }
}

// ---------------- launch ----------------
extern "C" void kernel_launch(void* const* d_in, const int* in_sizes, int n_in,
                              void* d_out, int out_size, void* d_ws, size_t ws_size,
                              hipStream_t stream) {
    const float* x      = (const float*)d_in[0];
    const float* hidden = (const float*)d_in[1];
    const float* Wf  = (const float*)d_in[2];
    const float* bf_ = (const float*)d_in[3];
    const float* Wi  = (const float*)d_in[4];
    const float* bi_ = (const float*)d_in[5];
    const float* Wig = (const float*)d_in[6];
    const float* big_= (const float*)d_in[7];
    const float* Wog = (const float*)d_in[8];
    const float* bog_= (const float*)d_in[9];

    char* ws = (char*)d_ws;
    unsigned short* Xb   = (unsigned short*)(ws);             // 33,554,432 B
    unsigned short* Wcat = (unsigned short*)(ws + 33554432);  //  8,388,608 B
    unsigned short* F    = (unsigned short*)(ws + 41943040);  // 33,554,432 B
    unsigned short* I    = (unsigned short*)(ws + 75497472);  // 33,554,432 B
    unsigned short* OG   = (unsigned short*)(ws + 109051904); // 33,554,432 B
    float* Aagg   = (float*)(ws + 142606336);                 //  1,048,576 B
    float* Bagg   = (float*)(ws + 143654912);                 //  1,048,576 B
    float* Hstart = (float*)(ws + 144703488);                 //  1,048,576 B
    // total ws need: 145,752,064 B

    float* y     = (float*)d_out;                 // [4][4096][1024]
    float* out_h = y + GATE_ELEMS;                // [4][1024]

    // fused casts (x: 8192 blocks, weights: 4 x 512 blocks)
    cast_all<<<10240, 256, 0, stream>>>(x, Wf, Wi, Wig, Wog, Xb, Wcat);

    // gate-fused GEMM + activations + i-product + scan-phase1 aggregates
    gemm_gates_f<<<2048, 512, 0, stream>>>(Xb, Wcat, bf_, bi_, big_, bog_,
                                           F, I, OG, Aagg, Bagg);

    // chunk-prefix scan + replay
    scan_phase2<<<BATCH * DIMD / 256, 256, 0, stream>>>(Aagg, Bagg, hidden, Hstart, out_h);
    scan_phase3<<<dim3(NCHUNK, BATCH), 256, 0, stream>>>(F, I, OG, Hstart, y);
}